// Round 5
// baseline (2338.740 us; speedup 1.0000x reference)
//
#include <hip/hip_runtime.h>
#include <hip/hip_bf16.h>

// HeteroGNN R8:
// - fillA group-routed: R7 PMC showed WRITE 353MB for 51MB payload even with
//   partition frontiers -> each 64B frontier line was written by ~8 XCDs whose
//   non-coherent L2s each write back a partial copy. Fix: 8 groups (bid&7 ->
//   XCD via round-robin dispatch), group g scans ALL edges but commits only
//   partitions with (p&7)==g -> every frontier line has ONE L2 owner ->
//   full-line writebacks. Edge re-reads (8x77MB) are L3-served (R7 fillA
//   FETCH was only 40MB).
// - fillB: per-partition LDS reorder to (dst,bucket) order (R7, ~66us).
// - agg: persistent generation-aligned convoy (R6, proven).
// - GEMM unchanged (8x8 register blocking, transposed padded A-tile).

#define RELS 4
#define HDIM 256
#define NB 16          // src buckets per dst (src>>13, src<100000 -> 0..12)
#define BSH 13
#define PSH 5          // dsts per partition = 32
#define PKEYS 512      // keys per partition = 32*16
#define PCAP 2816      // LDS edge capacity (Poisson(2048) + 17 sigma)

typedef float f32x4_t __attribute__((ext_vector_type(4)));
typedef unsigned short u16x8_t __attribute__((ext_vector_type(8)));

struct EdgePtrs {
    const int*   ei[RELS];
    const float* ew[RELS];
};

__device__ inline unsigned short f32_to_bf16_rne(float f) {
    unsigned int u = __float_as_uint(f);
    unsigned int r = 0x7FFFu + ((u >> 16) & 1u);
    return (unsigned short)((u + r) >> 16);
}

// ---------------- CSR build (keys = dst*NB + src_bucket) ----------------

__global__ __launch_bounds__(256) void count_kernel(EdgePtrs ep, int* __restrict__ cnts, int E) {
    int bpr = gridDim.x >> 2;
    int rel = blockIdx.x / bpr;
    int e = (blockIdx.x - rel * bpr) * 256 + threadIdx.x;
    if (e < E) {
        int src = ep.ei[rel][e];
        int dst = ep.ei[rel][E + e];
        atomicAdd(&cnts[(dst << 4) | (src >> BSH)], 1);
    }
}

template <int ITEMS>
__global__ __launch_bounds__(256) void scan_kernel(const int* __restrict__ in, int* __restrict__ out,
                                                   int* __restrict__ blockSums, int n) {
    __shared__ int wsum[4];
    int t = threadIdx.x;
    int base = blockIdx.x * 256 * ITEMS;
    int idx0 = base + t * ITEMS;
    int v[ITEMS];
    int local = 0;
#pragma unroll
    for (int j = 0; j < ITEMS; ++j) {
        v[j] = (idx0 + j < n) ? in[idx0 + j] : 0;
        local += v[j];
    }
    int lane = t & 63;
    int incl = local;
#pragma unroll
    for (int off = 1; off < 64; off <<= 1) {
        int y = __shfl_up(incl, off, 64);
        if (lane >= off) incl += y;
    }
    int waveId = t >> 6;
    if (lane == 63) wsum[waveId] = incl;
    __syncthreads();
    int waveOff = 0;
    for (int wi = 0; wi < waveId; ++wi) waveOff += wsum[wi];
    int run = waveOff + incl - local;
#pragma unroll
    for (int j = 0; j < ITEMS; ++j) {
        if (idx0 + j < n) out[idx0 + j] = run;
        run += v[j];
    }
    if (t == 255 && blockSums) blockSums[blockIdx.x] = waveOff + incl;
}

__global__ __launch_bounds__(256) void add_off_kernel(int* __restrict__ offs, const int* __restrict__ bsums,
                                                      int* __restrict__ pcur, int n) {
    int i = blockIdx.x * 256 + threadIdx.x;
    if (i < n) {
        int o = offs[i] + bsums[i >> 11];   // 2048 elems per L0 scan block
        offs[i] = o;
        if ((i & (PKEYS - 1)) == 0) pcur[i >> 9] = o;   // partition cursor init
    }
}

// fillA: group-routed scatter to 32-dst partition regions. gridDim.x = 8*bpg;
// group = bid&7 (round-robin -> one XCD per group); group g commits only
// partitions with (p&7)==g so each frontier line is owned by one L2.
// dstLocal packed in src bits 17-21 (src < 2^17).
__global__ __launch_bounds__(256) void fillA_kernel(EdgePtrs ep, int* __restrict__ pcur,
                                                    int2* __restrict__ stage, int E, int totE) {
    int grp = blockIdx.x & 7;
    int blk = blockIdx.x >> 3;
    int ge0 = blk * 4096;
    int relA = ge0 / E;              // slab (4096 <= E) spans at most 2 rels
    int bnd = (relA + 1) * E;
#pragma unroll
    for (int j = 0; j < 16; ++j) {
        int ge = ge0 + j * 256 + threadIdx.x;
        if (ge < totE) {
            int rel = (ge >= bnd) ? relA + 1 : relA;
            int off = ge - rel * E;
            int dst = ep.ei[rel][E + off];
            int p = dst >> PSH;
            if ((p & 7) == grp) {
                int src = ep.ei[rel][off];
                float w = ep.ew[rel][off];
                int pos = atomicAdd(&pcur[p], 1);
                stage[pos] = make_int2(src | ((dst & 31) << 17), __float_as_int(w));
            }
        }
    }
}

// fillB: one block per partition; reorder staged edges to (dst,bucket) order
// via LDS cursors, stream out dense. Fallback (cnt>PCAP): direct scatter.
__global__ __launch_bounds__(256) void fillB_kernel(const int2* __restrict__ stage,
                                                    const int* __restrict__ offs,
                                                    int2* __restrict__ epack,
                                                    int nKeys, int totE) {
    __shared__ int2 sbuf[PCAP];
    __shared__ int loc[PKEYS];
    int p = blockIdx.x;
    int kbase = p << 9;
    int base = offs[kbase];
    int kend = kbase + PKEYS;
    int cnt = ((kend < nKeys) ? offs[kend] : totE) - base;
    int t = threadIdx.x;
    for (int k = t; k < PKEYS; k += 256) {
        int gk = kbase + k;
        loc[k] = (gk < nKeys) ? (offs[gk] - base) : cnt;
    }
    __syncthreads();
    if (cnt <= PCAP) {
        for (int i = t; i < cnt; i += 256) {
            int2 r = stage[base + i];
            int src = r.x & 0x1FFFF;
            int key = ((r.x >> 17) << 4) | (src >> BSH);
            int pos = atomicAdd(&loc[key], 1);
            sbuf[pos] = make_int2(src, r.y);
        }
        __syncthreads();
        for (int i = t; i < cnt; i += 256)
            epack[base + i] = sbuf[i];
    } else {
        for (int i = t; i < cnt; i += 256) {
            int2 r = stage[base + i];
            int src = r.x & 0x1FFFF;
            int key = ((r.x >> 17) << 4) | (src >> BSH);
            int pos = atomicAdd(&loc[key], 1);
            epack[base + pos] = make_int2(src, r.y);
        }
    }
}

// ---------------- GEMM: [M,K] x [K,256] -> bf16 [M,256] ----------------

template <int K, bool FUSE>
__global__ __launch_bounds__(256) void gemm_kernel(const float* __restrict__ A, const float* __restrict__ W,
                                                   unsigned short* __restrict__ out, int M,
                                                   const float* __restrict__ stats,
                                                   const float* __restrict__ lnw, const float* __restrict__ lnb,
                                                   float invM) {
    __shared__ float At[K * 68];
    int t = threadIdx.x;
    int rowBase = blockIdx.x * 64;
    float m = 0.f, inv = 1.f;
    if (FUSE) {
        float s = stats[0], ss = stats[1];
        m = s * invM;
        float var = ss * invM - m * m;
        inv = 1.f / (sqrtf(fmaxf(var, 0.f)) + 1e-5f);
    }
    constexpr int KQ = K / 4;
    for (int idx = t; idx < 64 * KQ; idx += 256) {
        int row = idx / KQ;
        int kq = idx - row * KQ;
        int grow = rowBase + row;
        float4 a = make_float4(0.f, 0.f, 0.f, 0.f);
        if (grow < M) a = *(const float4*)&A[(size_t)grow * K + kq * 4];
        if (FUSE) {
            float4 w4 = *(const float4*)&lnw[kq * 4];
            float4 b4 = *(const float4*)&lnb[kq * 4];
            a.x = (a.x - m) * inv * w4.x + b4.x;
            a.y = (a.y - m) * inv * w4.y + b4.y;
            a.z = (a.z - m) * inv * w4.z + b4.z;
            a.w = (a.w - m) * inv * w4.w + b4.w;
        }
        At[(kq * 4 + 0) * 68 + row] = a.x;
        At[(kq * 4 + 1) * 68 + row] = a.y;
        At[(kq * 4 + 2) * 68 + row] = a.z;
        At[(kq * 4 + 3) * 68 + row] = a.w;
    }
    __syncthreads();

    int tx = t & 31;        // col base
    int ty = t >> 5;        // row group (8 rows)
    float acc[8][8];
#pragma unroll
    for (int i = 0; i < 8; ++i)
#pragma unroll
        for (int j = 0; j < 8; ++j) acc[i][j] = 0.f;

#pragma unroll 4
    for (int k = 0; k < K; ++k) {
        float4 a0 = *(const float4*)&At[k * 68 + (ty << 3)];
        float4 a1 = *(const float4*)&At[k * 68 + (ty << 3) + 4];
        float wv[8];
#pragma unroll
        for (int j = 0; j < 8; ++j) wv[j] = W[k * HDIM + tx + (j << 5)];
#pragma unroll
        for (int j = 0; j < 8; ++j) {
            acc[0][j] += a0.x * wv[j];
            acc[1][j] += a0.y * wv[j];
            acc[2][j] += a0.z * wv[j];
            acc[3][j] += a0.w * wv[j];
            acc[4][j] += a1.x * wv[j];
            acc[5][j] += a1.y * wv[j];
            acc[6][j] += a1.z * wv[j];
            acc[7][j] += a1.w * wv[j];
        }
    }
#pragma unroll
    for (int i = 0; i < 8; ++i) {
        int row = rowBase + (ty << 3) + i;
        if (row < M) {
#pragma unroll
            for (int j = 0; j < 8; ++j)
                out[((size_t)row << 8) + tx + (j << 5)] = f32_to_bf16_rne(acc[i][j]);
        }
    }
}

// ---------------- Aggregation: persistent, generation-aligned ----------------

__device__ inline void acc_fma8(float* a, float w, u16x8_t u) {
#pragma unroll
    for (int k = 0; k < 8; ++k)
        a[k] += w * __uint_as_float((unsigned)u[k] << 16);
}

__global__ __launch_bounds__(256) void agg_kernel(const unsigned short* __restrict__ Hf,
                                                  const int* __restrict__ offs,
                                                  const int2* __restrict__ epack,
                                                  const float* __restrict__ bias,
                                                  float* __restrict__ outp, float* __restrict__ stats,
                                                  int nNodes, int totE) {
    const int nwaves = (int)(gridDim.x << 2);
    const int wave0 = (blockIdx.x << 2) | (threadIdx.x >> 6);
    const int lane = threadIdx.x & 63;
    const int half = lane >> 5;
    const int cl = lane & 31;
    const unsigned short* __restrict__ hbase = Hf + cl * 8;
    const float4 b0 = *(const float4*)&bias[cl * 8];
    const float4 b1 = *(const float4*)&bias[cl * 8 + 4];
    float sum = 0.f, ssq = 0.f;

    for (int gwave = wave0; gwave < nNodes; gwave += nwaves) {
        float a[8];
#pragma unroll
        for (int k = 0; k < 8; ++k) a[k] = 0.f;

        int start = __builtin_amdgcn_readfirstlane(offs[gwave << 4]);
        int endv = (gwave + 1 < nNodes) ? offs[(gwave + 1) << 4] : totE;
        int cnt = __builtin_amdgcn_readfirstlane(endv) - start;
        const long long* ep = (const long long*)epack + start;
        int i = 0;
        for (; i + 12 <= cnt; i += 12) {
            long long q[6];
#pragma unroll
            for (int t = 0; t < 6; ++t) q[t] = ep[i + 2 * t + half];
            u16x8_t u[6];
#pragma unroll
            for (int t = 0; t < 6; ++t)
                u[t] = *(const u16x8_t*)&hbase[((size_t)(int)q[t]) << 8];
#pragma unroll
            for (int t = 0; t < 6; ++t)
                acc_fma8(a, __int_as_float((int)(q[t] >> 32)), u[t]);
        }
        for (; i + 2 <= cnt; i += 2) {
            long long q = ep[i + half];
            u16x8_t u = *(const u16x8_t*)&hbase[((size_t)(int)q) << 8];
            acc_fma8(a, __int_as_float((int)(q >> 32)), u);
        }
        if (i < cnt) {
            long long q = ep[i];
            u16x8_t u = *(const u16x8_t*)&hbase[((size_t)(int)q) << 8];
            float w = half ? 0.f : __int_as_float((int)(q >> 32));
            acc_fma8(a, w, u);
        }
#pragma unroll
        for (int k = 0; k < 8; ++k) a[k] += __shfl_xor(a[k], 32, 64);

        a[0] += b0.x; a[1] += b0.y; a[2] += b0.z; a[3] += b0.w;
        a[4] += b1.x; a[5] += b1.y; a[6] += b1.z; a[7] += b1.w;
        if (half == 0) {
            f32x4_t v0 = {a[0], a[1], a[2], a[3]};
            f32x4_t v1 = {a[4], a[5], a[6], a[7]};
            *(f32x4_t*)&outp[((size_t)gwave << 8) + cl * 8] = v0;
            *(f32x4_t*)&outp[((size_t)gwave << 8) + cl * 8 + 4] = v1;
#pragma unroll
            for (int k = 0; k < 8; ++k) { sum += a[k]; ssq += a[k] * a[k]; }
        }
    }

#pragma unroll
    for (int off = 32; off > 0; off >>= 1) {
        sum += __shfl_down(sum, off, 64);
        ssq += __shfl_down(ssq, off, 64);
    }
    __shared__ float ls[8];
    int wid = threadIdx.x >> 6;
    if ((threadIdx.x & 63) == 0) { ls[wid] = sum; ls[4 + wid] = ssq; }
    __syncthreads();
    if (threadIdx.x == 0) {
        atomicAdd(&stats[0], ls[0] + ls[1] + ls[2] + ls[3]);
        atomicAdd(&stats[1], ls[4] + ls[5] + ls[6] + ls[7]);
    }
}

// ---------------- Graph LayerNorm (elementwise, in-place, final) ----------------

__global__ __launch_bounds__(256) void ln_kernel(float* __restrict__ data, const float* __restrict__ stats,
                                                 const float* __restrict__ lw, const float* __restrict__ lb,
                                                 long long total, float invM) {
    long long i4 = (long long)blockIdx.x * 256 + threadIdx.x;
    long long idx = i4 * 4;
    if (idx >= total) return;
    float m = stats[0] * invM;
    float var = stats[1] * invM - m * m;
    float inv = 1.f / (sqrtf(fmaxf(var, 0.f)) + 1e-5f);
    float4 v = *(float4*)&data[idx];
    int c = (int)(idx & (HDIM - 1));
    float4 w = *(const float4*)&lw[c];
    float4 b = *(const float4*)&lb[c];
    v.x = (v.x - m) * inv * w.x + b.x;
    v.y = (v.y - m) * inv * w.y + b.y;
    v.z = (v.z - m) * inv * w.z + b.z;
    v.w = (v.w - m) * inv * w.w + b.w;
    *(float4*)&data[idx] = v;
}

// ---------------- launch ----------------

extern "C" void kernel_launch(void* const* d_in, const int* in_sizes, int n_in,
                              void* d_out, int out_size, void* d_ws, size_t ws_size,
                              hipStream_t stream) {
    const float* x = (const float*)d_in[0];
    EdgePtrs ep;
    ep.ei[0] = (const int*)d_in[1]; ep.ew[0] = (const float*)d_in[2];
    ep.ei[1] = (const int*)d_in[3]; ep.ew[1] = (const float*)d_in[4];
    ep.ei[2] = (const int*)d_in[5]; ep.ew[2] = (const float*)d_in[6];
    ep.ei[3] = (const int*)d_in[7]; ep.ew[3] = (const float*)d_in[8];
    const float* W1 = (const float*)d_in[9];
    const float* b1 = (const float*)d_in[10];
    const float* W2 = (const float*)d_in[11];
    const float* b2 = (const float*)d_in[12];
    const float* ln1w = (const float*)d_in[13];
    const float* ln1b = (const float*)d_in[14];
    const float* ln2w = (const float*)d_in[15];
    const float* ln2b = (const float*)d_in[16];

    const int N = in_sizes[0] / 128;  // 100000
    const int E = in_sizes[2];        // 1600000
    const int totE = RELS * E;
    const int nKeys = N * NB;         // 1.6M
    const int nParts = (N + 31) >> PSH;  // 3125
    float* out = (float*)d_out;

    // workspace layout
    char* ws = (char*)d_ws;
    unsigned short* Hbuf = (unsigned short*)ws;        // N*256 bf16 (51.2 MB); doubles as fill staging
    int2* epack = (int2*)(Hbuf + (size_t)N * HDIM);    // totE int2 (51.2 MB)
    int* cnts = (int*)(epack + totE);                  // nKeys (6.4 MB)
    int* offs = cnts + nKeys;                          // nKeys
    int* pcur = offs + nKeys;                          // nKeys region (uses first nParts)
    int* bsums = pcur + nKeys;                         // 1024
    float* stats = (float*)(bsums + 1024);             // 4 floats

    hipMemsetAsync(cnts, 0, (size_t)nKeys * sizeof(int), stream);
    hipMemsetAsync(stats, 0, 4 * sizeof(float), stream);

    int bpr = (E + 255) / 256;
    count_kernel<<<RELS * bpr, 256, 0, stream>>>(ep, cnts, E);
    int nb1 = (nKeys + 2047) / 2048;   // 782 L0 blocks (ITEMS=8)
    scan_kernel<8><<<nb1, 256, 0, stream>>>(cnts, offs, bsums, nKeys);
    scan_kernel<4><<<1, 256, 0, stream>>>(bsums, bsums, nullptr, nb1);
    add_off_kernel<<<(nKeys + 255) / 256, 256, 0, stream>>>(offs, bsums, pcur, nKeys);
    int bpg = (totE + 4095) / 4096;   // slab blocks per group
    fillA_kernel<<<8 * bpg, 256, 0, stream>>>(ep, pcur, (int2*)Hbuf, E, totE);
    fillB_kernel<<<nParts, 256, 0, stream>>>((const int2*)Hbuf, offs, epack, nKeys, totE);

    long long total = (long long)N * HDIM;
    float invM = 1.f / (float)total;
    int gemmGrid = (N + 63) / 64;
    // persistent agg grid: exactly resident capacity (8 blocks/CU x 256 CU);
    // generation-aligned dst mapping keeps all waves in the same src-bucket
    // window -> per-XCD L2 locality without grid.sync.
    int aggGrid = (N + 3) / 4;
    if (aggGrid > 2048) aggGrid = 2048;
    int lnGrid = (int)((total / 4 + 255) / 256);

    // Layer 1: x@W1 -> Hbuf(bf16) ; agg -> d_out (+stats0)
    gemm_kernel<128, false><<<gemmGrid, 256, 0, stream>>>(x, W1, Hbuf, N, nullptr, nullptr, nullptr, invM);
    agg_kernel<<<aggGrid, 256, 0, stream>>>(Hbuf, offs, epack, b1, out, stats, N, totE);

    // Layer 2: LN1 fused into GEMM2 staging ; agg -> d_out (+stats1) ; LN2
    gemm_kernel<256, true><<<gemmGrid, 256, 0, stream>>>(out, W2, Hbuf, N, stats, ln1w, ln1b, invM);
    agg_kernel<<<aggGrid, 256, 0, stream>>>(Hbuf, offs, epack, b2, out, stats + 2, N, totE);
    ln_kernel<<<lnGrid, 256, 0, stream>>>(out, stats + 2, ln2w, ln2b, total, invM);
}

// Round 6
// 1632.916 us; speedup vs baseline: 1.4322x; 1.4322x over previous
//
#include <hip/hip_runtime.h>
#include <hip/hip_bf16.h>

// HeteroGNN R9:
// - CSR build rewritten as a 2-level LDS-staged counting sort. R7/R8 PMC
//   showed random 8B scatters cost 5-8x write amplification (partial-line
//   writebacks; streaming reads evict half-filled dirty lines). Here every
//   global write is a dense run produced by ONE block in one short window:
//   histA (LDS hist over 782 coarse partitions) -> deterministic run bases
//   (scan) -> scatA (runs of ~256B, no global atomics) -> fillB (per-
//   partition fine sort in LDS, writes offs CSR as byproduct -> count/scan/
//   add_off kernels deleted) -> dense epack.
// - agg: persistent generation-aligned convoy (R6, proven best).
// - GEMM unchanged (8x8 register blocking, transposed padded A-tile).

#define RELS 4
#define HDIM 256
#define NB 16          // src buckets per dst (src>>13, src<100000 -> 0..12)
#define BSH 13
#define PBITS 7        // dsts per partition = 128
#define PKEYS2 2048    // fine keys per partition = 128*16
#define NA 256         // scatter blocks (= runscan blockDim)
#define MAXPARTS 784
#define BCAP 8832      // LDS edge capacity per partition (8192 + 7 sigma)

typedef float f32x4_t __attribute__((ext_vector_type(4)));
typedef unsigned short u16x8_t __attribute__((ext_vector_type(8)));

struct EdgePtrs {
    const int*   ei[RELS];
    const float* ew[RELS];
};

__device__ inline unsigned short f32_to_bf16_rne(float f) {
    unsigned int u = __float_as_uint(f);
    unsigned int r = 0x7FFFu + ((u >> 16) & 1u);
    return (unsigned short)((u + r) >> 16);
}

// ---------------- level A: coarse partition (dst>>7) ----------------

__global__ __launch_bounds__(512) void histA_kernel(EdgePtrs ep, int* __restrict__ hist,
                                                    int* __restrict__ ptot,
                                                    int E, int totE, int CH, int nParts) {
    __shared__ int h[MAXPARTS];
    int t = threadIdx.x;
    for (int k = t; k < nParts; k += 512) h[k] = 0;
    __syncthreads();
    int g0 = blockIdx.x * CH;
    int relA = g0 / E;
    int bnd = (relA + 1) * E;
    int gend = g0 + CH; if (gend > totE) gend = totE;
    for (int ge = g0 + t; ge < gend; ge += 512) {
        int rel = (ge >= bnd) ? relA + 1 : relA;
        int off = ge - rel * E;
        int dst = ep.ei[rel][E + off];
        atomicAdd(&h[dst >> PBITS], 1);
    }
    __syncthreads();
    for (int k = t; k < nParts; k += 512) {
        int c = h[k];
        hist[k * NA + blockIdx.x] = c;
        if (c) atomicAdd(&ptot[k], c);
    }
}

template <int ITEMS>
__global__ __launch_bounds__(256) void scan_kernel(const int* __restrict__ in, int* __restrict__ out,
                                                   int* __restrict__ blockSums, int n) {
    __shared__ int wsum[4];
    int t = threadIdx.x;
    int base = blockIdx.x * 256 * ITEMS;
    int idx0 = base + t * ITEMS;
    int v[ITEMS];
    int local = 0;
#pragma unroll
    for (int j = 0; j < ITEMS; ++j) {
        v[j] = (idx0 + j < n) ? in[idx0 + j] : 0;
        local += v[j];
    }
    int lane = t & 63;
    int incl = local;
#pragma unroll
    for (int off = 1; off < 64; off <<= 1) {
        int y = __shfl_up(incl, off, 64);
        if (lane >= off) incl += y;
    }
    int waveId = t >> 6;
    if (lane == 63) wsum[waveId] = incl;
    __syncthreads();
    int waveOff = 0;
    for (int wi = 0; wi < waveId; ++wi) waveOff += wsum[wi];
    int run = waveOff + incl - local;
#pragma unroll
    for (int j = 0; j < ITEMS; ++j) {
        if (idx0 + j < n) out[idx0 + j] = run;
        run += v[j];
    }
    if (t == 255 && blockSums) blockSums[blockIdx.x] = waveOff + incl;
}

// exclusive scan of hist[p][0..NA) + coarse[p] -> run bases (in place)
__global__ __launch_bounds__(NA) void runscan_kernel(int* __restrict__ hist, const int* __restrict__ coarse) {
    __shared__ int wsum[4];
    int p = blockIdx.x;
    int t = threadIdx.x;
    int v = hist[p * NA + t];
    int lane = t & 63;
    int incl = v;
#pragma unroll
    for (int off = 1; off < 64; off <<= 1) {
        int y = __shfl_up(incl, off, 64);
        if (lane >= off) incl += y;
    }
    int waveId = t >> 6;
    if (lane == 63) wsum[waveId] = incl;
    __syncthreads();
    int waveOff = 0;
    for (int wi = 0; wi < waveId; ++wi) waveOff += wsum[wi];
    hist[p * NA + t] = coarse[p] + waveOff + incl - v;
}

// scatter edges into partition-major stage; each (partition,block) run is
// written densely by one block (no global atomics; bases are deterministic).
// stage entry: low32 = src | dstLocal<<17 ; high32 = w bits.
__global__ __launch_bounds__(512) void scatA_kernel(EdgePtrs ep, const int* __restrict__ runBase,
                                                    long long* __restrict__ stage,
                                                    int E, int totE, int CH, int nParts) {
    __shared__ int cur[MAXPARTS];
    int t = threadIdx.x;
    for (int k = t; k < nParts; k += 512) cur[k] = runBase[k * NA + blockIdx.x];
    __syncthreads();
    int g0 = blockIdx.x * CH;
    int relA = g0 / E;
    int bnd = (relA + 1) * E;
    int gend = g0 + CH; if (gend > totE) gend = totE;
    for (int ge = g0 + t; ge < gend; ge += 512) {
        int rel = (ge >= bnd) ? relA + 1 : relA;
        int off = ge - rel * E;
        int src = ep.ei[rel][off];
        int dst = ep.ei[rel][E + off];
        unsigned int w = __float_as_uint(ep.ew[rel][off]);
        int p = dst >> PBITS;
        int pos = atomicAdd(&cur[p], 1);
        stage[pos] = ((long long)w << 32) | (unsigned int)(src | ((dst & 127) << 17));
    }
}

// ---------------- level B: fine sort within partition + offs CSR ----------------

__global__ __launch_bounds__(256, 2) void fillB_kernel(const long long* __restrict__ stage,
                                                       const int* __restrict__ coarse,
                                                       long long* __restrict__ epack,
                                                       int* __restrict__ offs,
                                                       int nParts, int nKeys, int totE) {
    __shared__ long long sbuf[BCAP];
    __shared__ int loc[PKEYS2];
    __shared__ int wsum[4];
    int p = blockIdx.x;
    int t = threadIdx.x;
    int base = coarse[p];
    int cnt = ((p + 1 < nParts) ? coarse[p + 1] : totE) - base;
    for (int k = t; k < PKEYS2; k += 256) loc[k] = 0;
    __syncthreads();
    // pass 1: fine-key histogram
    for (int i = t; i < cnt; i += 256) {
        int lo = (int)stage[base + i];
        int key = (((lo >> 17) & 127) << 4) | ((lo & 0x1FFFF) >> BSH);
        atomicAdd(&loc[key], 1);
    }
    __syncthreads();
    // scan 2048 keys (8 per thread); write global offs as byproduct
    int vv[8];
    int local = 0;
    int t8 = t << 3;
#pragma unroll
    for (int j = 0; j < 8; ++j) { vv[j] = loc[t8 + j]; local += vv[j]; }
    int lane = t & 63;
    int incl = local;
#pragma unroll
    for (int off = 1; off < 64; off <<= 1) {
        int y = __shfl_up(incl, off, 64);
        if (lane >= off) incl += y;
    }
    int waveId = t >> 6;
    if (lane == 63) wsum[waveId] = incl;
    __syncthreads();
    int waveOff = 0;
    for (int wi = 0; wi < waveId; ++wi) waveOff += wsum[wi];
    int run = waveOff + incl - local;
    int kbase = p << 11;
#pragma unroll
    for (int j = 0; j < 8; ++j) {
        loc[t8 + j] = run;
        int gk = kbase + t8 + j;
        if (gk < nKeys) offs[gk] = base + run;
        run += vv[j];
    }
    __syncthreads();
    // pass 2: scatter into LDS, stream out dense
    if (cnt <= BCAP) {
        for (int i = t; i < cnt; i += 256) {
            long long q = stage[base + i];
            int lo = (int)q;
            int src = lo & 0x1FFFF;
            int key = (((lo >> 17) & 127) << 4) | (src >> BSH);
            int pos = atomicAdd(&loc[key], 1);
            sbuf[pos] = (q & 0xFFFFFFFF00000000LL) | (unsigned int)src;
        }
        __syncthreads();
        for (int i = t; i < cnt; i += 256) epack[base + i] = sbuf[i];
    } else {  // overflow fallback (statistically never at Poisson(8192)+7sigma)
        for (int i = t; i < cnt; i += 256) {
            long long q = stage[base + i];
            int lo = (int)q;
            int src = lo & 0x1FFFF;
            int key = (((lo >> 17) & 127) << 4) | (src >> BSH);
            int pos = atomicAdd(&loc[key], 1);
            epack[base + pos] = (q & 0xFFFFFFFF00000000LL) | (unsigned int)src;
        }
    }
}

// ---------------- GEMM: [M,K] x [K,256] -> bf16 [M,256] ----------------

template <int K, bool FUSE>
__global__ __launch_bounds__(256) void gemm_kernel(const float* __restrict__ A, const float* __restrict__ W,
                                                   unsigned short* __restrict__ out, int M,
                                                   const float* __restrict__ stats,
                                                   const float* __restrict__ lnw, const float* __restrict__ lnb,
                                                   float invM) {
    __shared__ float At[K * 68];
    int t = threadIdx.x;
    int rowBase = blockIdx.x * 64;
    float m = 0.f, inv = 1.f;
    if (FUSE) {
        float s = stats[0], ss = stats[1];
        m = s * invM;
        float var = ss * invM - m * m;
        inv = 1.f / (sqrtf(fmaxf(var, 0.f)) + 1e-5f);
    }
    constexpr int KQ = K / 4;
    for (int idx = t; idx < 64 * KQ; idx += 256) {
        int row = idx / KQ;
        int kq = idx - row * KQ;
        int grow = rowBase + row;
        float4 a = make_float4(0.f, 0.f, 0.f, 0.f);
        if (grow < M) a = *(const float4*)&A[(size_t)grow * K + kq * 4];
        if (FUSE) {
            float4 w4 = *(const float4*)&lnw[kq * 4];
            float4 b4 = *(const float4*)&lnb[kq * 4];
            a.x = (a.x - m) * inv * w4.x + b4.x;
            a.y = (a.y - m) * inv * w4.y + b4.y;
            a.z = (a.z - m) * inv * w4.z + b4.z;
            a.w = (a.w - m) * inv * w4.w + b4.w;
        }
        At[(kq * 4 + 0) * 68 + row] = a.x;
        At[(kq * 4 + 1) * 68 + row] = a.y;
        At[(kq * 4 + 2) * 68 + row] = a.z;
        At[(kq * 4 + 3) * 68 + row] = a.w;
    }
    __syncthreads();

    int tx = t & 31;        // col base
    int ty = t >> 5;        // row group (8 rows)
    float acc[8][8];
#pragma unroll
    for (int i = 0; i < 8; ++i)
#pragma unroll
        for (int j = 0; j < 8; ++j) acc[i][j] = 0.f;

#pragma unroll 4
    for (int k = 0; k < K; ++k) {
        float4 a0 = *(const float4*)&At[k * 68 + (ty << 3)];
        float4 a1 = *(const float4*)&At[k * 68 + (ty << 3) + 4];
        float wv[8];
#pragma unroll
        for (int j = 0; j < 8; ++j) wv[j] = W[k * HDIM + tx + (j << 5)];
#pragma unroll
        for (int j = 0; j < 8; ++j) {
            acc[0][j] += a0.x * wv[j];
            acc[1][j] += a0.y * wv[j];
            acc[2][j] += a0.z * wv[j];
            acc[3][j] += a0.w * wv[j];
            acc[4][j] += a1.x * wv[j];
            acc[5][j] += a1.y * wv[j];
            acc[6][j] += a1.z * wv[j];
            acc[7][j] += a1.w * wv[j];
        }
    }
#pragma unroll
    for (int i = 0; i < 8; ++i) {
        int row = rowBase + (ty << 3) + i;
        if (row < M) {
#pragma unroll
            for (int j = 0; j < 8; ++j)
                out[((size_t)row << 8) + tx + (j << 5)] = f32_to_bf16_rne(acc[i][j]);
        }
    }
}

// ---------------- Aggregation: persistent, generation-aligned ----------------

__device__ inline void acc_fma8(float* a, float w, u16x8_t u) {
#pragma unroll
    for (int k = 0; k < 8; ++k)
        a[k] += w * __uint_as_float((unsigned)u[k] << 16);
}

__global__ __launch_bounds__(256) void agg_kernel(const unsigned short* __restrict__ Hf,
                                                  const int* __restrict__ offs,
                                                  const int2* __restrict__ epack,
                                                  const float* __restrict__ bias,
                                                  float* __restrict__ outp, float* __restrict__ stats,
                                                  int nNodes, int totE) {
    const int nwaves = (int)(gridDim.x << 2);
    const int wave0 = (blockIdx.x << 2) | (threadIdx.x >> 6);
    const int lane = threadIdx.x & 63;
    const int half = lane >> 5;
    const int cl = lane & 31;
    const unsigned short* __restrict__ hbase = Hf + cl * 8;
    const float4 b0 = *(const float4*)&bias[cl * 8];
    const float4 b1 = *(const float4*)&bias[cl * 8 + 4];
    float sum = 0.f, ssq = 0.f;

    for (int gwave = wave0; gwave < nNodes; gwave += nwaves) {
        float a[8];
#pragma unroll
        for (int k = 0; k < 8; ++k) a[k] = 0.f;

        int start = __builtin_amdgcn_readfirstlane(offs[gwave << 4]);
        int endv = (gwave + 1 < nNodes) ? offs[(gwave + 1) << 4] : totE;
        int cnt = __builtin_amdgcn_readfirstlane(endv) - start;
        const long long* ep = (const long long*)epack + start;
        int i = 0;
        for (; i + 12 <= cnt; i += 12) {
            long long q[6];
#pragma unroll
            for (int t = 0; t < 6; ++t) q[t] = ep[i + 2 * t + half];
            u16x8_t u[6];
#pragma unroll
            for (int t = 0; t < 6; ++t)
                u[t] = *(const u16x8_t*)&hbase[((size_t)(int)q[t]) << 8];
#pragma unroll
            for (int t = 0; t < 6; ++t)
                acc_fma8(a, __int_as_float((int)(q[t] >> 32)), u[t]);
        }
        for (; i + 2 <= cnt; i += 2) {
            long long q = ep[i + half];
            u16x8_t u = *(const u16x8_t*)&hbase[((size_t)(int)q) << 8];
            acc_fma8(a, __int_as_float((int)(q >> 32)), u);
        }
        if (i < cnt) {
            long long q = ep[i];
            u16x8_t u = *(const u16x8_t*)&hbase[((size_t)(int)q) << 8];
            float w = half ? 0.f : __int_as_float((int)(q >> 32));
            acc_fma8(a, w, u);
        }
#pragma unroll
        for (int k = 0; k < 8; ++k) a[k] += __shfl_xor(a[k], 32, 64);

        a[0] += b0.x; a[1] += b0.y; a[2] += b0.z; a[3] += b0.w;
        a[4] += b1.x; a[5] += b1.y; a[6] += b1.z; a[7] += b1.w;
        if (half == 0) {
            f32x4_t v0 = {a[0], a[1], a[2], a[3]};
            f32x4_t v1 = {a[4], a[5], a[6], a[7]};
            *(f32x4_t*)&outp[((size_t)gwave << 8) + cl * 8] = v0;
            *(f32x4_t*)&outp[((size_t)gwave << 8) + cl * 8 + 4] = v1;
#pragma unroll
            for (int k = 0; k < 8; ++k) { sum += a[k]; ssq += a[k] * a[k]; }
        }
    }

#pragma unroll
    for (int off = 32; off > 0; off >>= 1) {
        sum += __shfl_down(sum, off, 64);
        ssq += __shfl_down(ssq, off, 64);
    }
    __shared__ float ls[8];
    int wid = threadIdx.x >> 6;
    if ((threadIdx.x & 63) == 0) { ls[wid] = sum; ls[4 + wid] = ssq; }
    __syncthreads();
    if (threadIdx.x == 0) {
        atomicAdd(&stats[0], ls[0] + ls[1] + ls[2] + ls[3]);
        atomicAdd(&stats[1], ls[4] + ls[5] + ls[6] + ls[7]);
    }
}

// ---------------- Graph LayerNorm (elementwise, in-place, final) ----------------

__global__ __launch_bounds__(256) void ln_kernel(float* __restrict__ data, const float* __restrict__ stats,
                                                 const float* __restrict__ lw, const float* __restrict__ lb,
                                                 long long total, float invM) {
    long long i4 = (long long)blockIdx.x * 256 + threadIdx.x;
    long long idx = i4 * 4;
    if (idx >= total) return;
    float m = stats[0] * invM;
    float var = stats[1] * invM - m * m;
    float inv = 1.f / (sqrtf(fmaxf(var, 0.f)) + 1e-5f);
    float4 v = *(float4*)&data[idx];
    int c = (int)(idx & (HDIM - 1));
    float4 w = *(const float4*)&lw[c];
    float4 b = *(const float4*)&lb[c];
    v.x = (v.x - m) * inv * w.x + b.x;
    v.y = (v.y - m) * inv * w.y + b.y;
    v.z = (v.z - m) * inv * w.z + b.z;
    v.w = (v.w - m) * inv * w.w + b.w;
    *(float4*)&data[idx] = v;
}

// ---------------- launch ----------------

extern "C" void kernel_launch(void* const* d_in, const int* in_sizes, int n_in,
                              void* d_out, int out_size, void* d_ws, size_t ws_size,
                              hipStream_t stream) {
    const float* x = (const float*)d_in[0];
    EdgePtrs ep;
    ep.ei[0] = (const int*)d_in[1]; ep.ew[0] = (const float*)d_in[2];
    ep.ei[1] = (const int*)d_in[3]; ep.ew[1] = (const float*)d_in[4];
    ep.ei[2] = (const int*)d_in[5]; ep.ew[2] = (const float*)d_in[6];
    ep.ei[3] = (const int*)d_in[7]; ep.ew[3] = (const float*)d_in[8];
    const float* W1 = (const float*)d_in[9];
    const float* b1 = (const float*)d_in[10];
    const float* W2 = (const float*)d_in[11];
    const float* b2 = (const float*)d_in[12];
    const float* ln1w = (const float*)d_in[13];
    const float* ln1b = (const float*)d_in[14];
    const float* ln2w = (const float*)d_in[15];
    const float* ln2b = (const float*)d_in[16];

    const int N = in_sizes[0] / 128;  // 100000
    const int E = in_sizes[2];        // 1600000
    const int totE = RELS * E;
    const int nKeys = N * NB;         // 1.6M
    const int nParts = (N + 127) >> PBITS;  // 782
    const int CH = (totE + NA - 1) / NA;    // 25000
    float* out = (float*)d_out;

    // workspace layout
    char* ws = (char*)d_ws;
    unsigned short* Hbuf = (unsigned short*)ws;        // N*256 bf16 (51.2 MB); aliases sort stage (totE*8B)
    long long* stage = (long long*)ws;
    long long* epack = (long long*)(Hbuf + (size_t)N * HDIM);  // totE*8B (51.2 MB)
    int* offs = (int*)(epack + totE);                  // nKeys (6.4 MB)
    int* hist = offs + nKeys;                          // MAXPARTS*NA (~800 KB)
    int* ptot = hist + MAXPARTS * NA;                  // 1024
    int* coarse = ptot + 1024;                         // 1024
    float* stats = (float*)(coarse + 1024);            // 4 floats

    hipMemsetAsync(ptot, 0, 1024 * sizeof(int), stream);
    hipMemsetAsync(stats, 0, 4 * sizeof(float), stream);

    histA_kernel<<<NA, 512, 0, stream>>>(ep, hist, ptot, E, totE, CH, nParts);
    scan_kernel<4><<<1, 256, 0, stream>>>(ptot, coarse, nullptr, nParts);
    runscan_kernel<<<nParts, NA, 0, stream>>>(hist, coarse);
    scatA_kernel<<<NA, 512, 0, stream>>>(ep, hist, stage, E, totE, CH, nParts);
    fillB_kernel<<<nParts, 256, 0, stream>>>(stage, coarse, epack, offs, nParts, nKeys, totE);

    long long total = (long long)N * HDIM;
    float invM = 1.f / (float)total;
    int gemmGrid = (N + 63) / 64;
    // persistent agg grid: exactly resident capacity (8 blocks/CU x 256 CU);
    // generation-aligned dst mapping keeps all waves in the same src-bucket
    // window -> per-XCD L2 locality without grid.sync.
    int aggGrid = (N + 3) / 4;
    if (aggGrid > 2048) aggGrid = 2048;
    int lnGrid = (int)((total / 4 + 255) / 256);

    // Layer 1: x@W1 -> Hbuf(bf16) ; agg -> d_out (+stats0)
    gemm_kernel<128, false><<<gemmGrid, 256, 0, stream>>>(x, W1, Hbuf, N, nullptr, nullptr, nullptr, invM);
    agg_kernel<<<aggGrid, 256, 0, stream>>>(Hbuf, offs, (const int2*)epack, b1, out, stats, N, totE);

    // Layer 2: LN1 fused into GEMM2 staging ; agg -> d_out (+stats1) ; LN2
    gemm_kernel<256, true><<<gemmGrid, 256, 0, stream>>>(out, W2, Hbuf, N, stats, ln1w, ln1b, invM);
    agg_kernel<<<aggGrid, 256, 0, stream>>>(Hbuf, offs, (const int2*)epack, b2, out, stats + 2, N, totE);
    ln_kernel<<<lnGrid, 256, 0, stream>>>(out, stats + 2, ln2w, ln2b, total, invM);
}